// Round 4
// baseline (32.565 us; speedup 1.0000x reference)
//
#include <hip/hip_runtime.h>

typedef _Float16 h2 __attribute__((ext_vector_type(2)));
typedef _Float16 h4 __attribute__((ext_vector_type(4)));
typedef unsigned u4 __attribute__((ext_vector_type(4)));

#define NCTX   512
#define NHEADS 8
#define WIDTH  64
#define TI     32
#define TJ     32
#define PAD    72          // halves; 144 B row stride = 36 dwords -> balanced bank tiling
#define ROWS   256         // 32 rows x 8 heads
#define LDS_BYTES (2 * ROWS * PAD * 2)   // 73728 -> 2 blocks/CU

__global__ __launch_bounds__(512, 4)
void l1attn_kernel(const float* __restrict__ qg, const float* __restrict__ kg,
                   float* __restrict__ out) {
    extern __shared__ __align__(16) _Float16 smem[];
    _Float16* qs = smem;              // [256 rows = j*8+h][PAD]
    _Float16* ks = smem + ROWS * PAD; // [256 rows = i*8+h][PAD]

    const int t = threadIdx.x;

    // XCD-aware decode: blocks sharing a j-tile (same q slice) land on one XCD.
    const int bid  = blockIdx.x;        // 0..511
    const int xcd  = bid & 7;
    const int slot = bid >> 3;          // 0..63
    const int jt   = xcd * 2 + (slot >> 5);
    const int it   = slot & 15;
    const int b    = (slot >> 4) & 1;
    const int i0   = it * TI;
    const int j0   = jt * TJ;

    // ---- stage: issue ALL 16 global loads first, then convert + LDS-write ----
    const float4* qsrc = (const float4*)(qg + ((size_t)b * NCTX + j0) * (NHEADS * WIDTH));
    const float4* ksrc = (const float4*)(kg + ((size_t)b * NCTX + i0) * (NHEADS * WIDTH));
    float4 qv4[8], kv4[8];
    #pragma unroll
    for (int rr = 0; rr < 8; ++rr) qv4[rr] = qsrc[t + rr * 512];
    #pragma unroll
    for (int rr = 0; rr < 8; ++rr) kv4[rr] = ksrc[t + rr * 512];

    #pragma unroll
    for (int rr = 0; rr < 8; ++rr) {
        int f = t + rr * 512;                 // float4 index; row = f>>4, w4 = f&15
        float4 v = qv4[rr];
        h2 lo = __builtin_bit_cast(h2, __builtin_amdgcn_cvt_pkrtz(v.x, v.y));
        h2 hi = __builtin_bit_cast(h2, __builtin_amdgcn_cvt_pkrtz(v.z, v.w));
        h4 pk = {lo.x, lo.y, hi.x, hi.y};
        *(h4*)(qs + (f >> 4) * PAD + (f & 15) * 4) = pk;
    }
    #pragma unroll
    for (int rr = 0; rr < 8; ++rr) {
        int f = t + rr * 512;
        float4 v = kv4[rr];
        h2 lo = __builtin_bit_cast(h2, __builtin_amdgcn_cvt_pkrtz(v.x, v.y));
        h2 hi = __builtin_bit_cast(h2, __builtin_amdgcn_cvt_pkrtz(v.z, v.w));
        h4 pk = {lo.x, lo.y, hi.x, hi.y};
        *(h4*)(ks + (f >> 4) * PAD + (f & 15) * 4) = pk;
    }
    __syncthreads();

    // ---- compute: wave w, lane l: h = l&7, j-sub = l>>3; m extends j, n extends i ----
    const int w = t >> 6;
    const int l = t & 63;
    const int h = l & 7;

    const h2 one2 = {(_Float16)1.f, (_Float16)1.f};
    const float s = -0.125f;   // -1/sqrt(64)

    const _Float16* qrow = qs + (size_t)l * PAD;             // + 64m*PAD per chunk
    const _Float16* krow = ks + (size_t)(8 * w + h) * PAD;   // + 64n*PAD per n

    #pragma unroll 1
    for (int m = 0; m < 4; ++m) {
        float acc[4] = {0.f, 0.f, 0.f, 0.f};
        #pragma unroll
        for (int w8 = 0; w8 < 8; ++w8) {
            u4 qd = *(const u4*)(qrow + (size_t)(64 * m) * PAD + 8 * w8);
            u4 kd[4];
            #pragma unroll
            for (int n = 0; n < 4; ++n)
                kd[n] = *(const u4*)(krow + (size_t)(64 * n) * PAD + 8 * w8);
            #pragma unroll
            for (int n = 0; n < 4; ++n)
                #pragma unroll
                for (int p = 0; p < 4; ++p) {
                    h2 a = __builtin_bit_cast(h2, (unsigned)qd[p]);
                    h2 c = __builtin_bit_cast(h2, (unsigned)kd[n][p]);
                    h2 d = a - c;                                   // v_pk_add_f16 (neg)
                    d = __builtin_bit_cast(h2,
                            __builtin_bit_cast(unsigned, d) & 0x7fff7fffu);  // packed |.|
                    acc[n] = __builtin_amdgcn_fdot2(d, one2, acc[n], false);
                }
        }
        // ---- streamed coalesced stores: 64 lanes = 64 consecutive dwords ----
        #pragma unroll
        for (int n = 0; n < 4; ++n) {
            size_t base = (((size_t)b * NCTX + (i0 + w + 8 * n)) * NCTX + j0 + 8 * m) * NHEADS;
            out[base + l] = acc[n] * s;
        }
    }
}

extern "C" void kernel_launch(void* const* d_in, const int* in_sizes, int n_in,
                              void* d_out, int out_size, void* d_ws, size_t ws_size,
                              hipStream_t stream) {
    const float* q = (const float*)d_in[0];
    const float* k = (const float*)d_in[1];
    float* out = (float*)d_out;

    (void)hipFuncSetAttribute(reinterpret_cast<const void*>(l1attn_kernel),
                              hipFuncAttributeMaxDynamicSharedMemorySize, LDS_BYTES);

    l1attn_kernel<<<dim3(512), dim3(512), LDS_BYTES, stream>>>(q, k, out);
}

// Round 5
// 22.067 us; speedup vs baseline: 1.4757x; 1.4757x over previous
//
#include <hip/hip_runtime.h>

typedef _Float16 h2 __attribute__((ext_vector_type(2)));
typedef _Float16 h4 __attribute__((ext_vector_type(4)));
typedef unsigned u4 __attribute__((ext_vector_type(4)));

#define NCTX   512
#define NHEADS 8
#define WIDTH  64
#define TI     32
#define TJ     32
#define PAD    72          // halves; 144 B row stride = 36 dwords -> lanes tile all 32 banks
#define ROWS   256         // 32 rows x 8 heads
#define LDS_BYTES (2 * ROWS * PAD * 2)   // 73728 -> 2 blocks/CU

__global__ __launch_bounds__(512, 4)
void l1attn_kernel(const float* __restrict__ qg, const float* __restrict__ kg,
                   float* __restrict__ out) {
    extern __shared__ __align__(16) _Float16 smem[];
    _Float16* qs = smem;              // [256 rows = j*8+h][PAD]
    _Float16* ks = smem + ROWS * PAD; // [256 rows = i*8+h][PAD]

    const int t = threadIdx.x;

    // XCD-aware decode: blocks sharing a j-tile (same q slice) land on one XCD.
    const int bid  = blockIdx.x;        // 0..511
    const int xcd  = bid & 7;
    const int slot = bid >> 3;          // 0..63
    const int jt   = xcd * 2 + (slot >> 5);
    const int it   = slot & 15;
    const int b    = (slot >> 4) & 1;
    const int i0   = it * TI;
    const int j0   = jt * TJ;

    // ---- stage: issue all 16 global loads, then convert + LDS-write ----
    const float4* qsrc = (const float4*)(qg + ((size_t)b * NCTX + j0) * (NHEADS * WIDTH));
    const float4* ksrc = (const float4*)(kg + ((size_t)b * NCTX + i0) * (NHEADS * WIDTH));
    float4 qv4[8], kv4[8];
    #pragma unroll
    for (int rr = 0; rr < 8; ++rr) qv4[rr] = qsrc[t + rr * 512];
    #pragma unroll
    for (int rr = 0; rr < 8; ++rr) kv4[rr] = ksrc[t + rr * 512];

    #pragma unroll
    for (int rr = 0; rr < 8; ++rr) {
        int f = t + rr * 512;                 // float4 index; row = f>>4, w4 = f&15
        float4 v = qv4[rr];
        h2 lo = __builtin_bit_cast(h2, __builtin_amdgcn_cvt_pkrtz(v.x, v.y));
        h2 hi = __builtin_bit_cast(h2, __builtin_amdgcn_cvt_pkrtz(v.z, v.w));
        h4 pk = {lo.x, lo.y, hi.x, hi.y};
        *(h4*)(qs + (f >> 4) * PAD + (f & 15) * 4) = pk;
    }
    #pragma unroll
    for (int rr = 0; rr < 8; ++rr) {
        int f = t + rr * 512;
        float4 v = kv4[rr];
        h2 lo = __builtin_bit_cast(h2, __builtin_amdgcn_cvt_pkrtz(v.x, v.y));
        h2 hi = __builtin_bit_cast(h2, __builtin_amdgcn_cvt_pkrtz(v.z, v.w));
        h4 pk = {lo.x, lo.y, hi.x, hi.y};
        *(h4*)(ks + (f >> 4) * PAD + (f & 15) * 4) = pk;
    }
    __syncthreads();

    // ---- compute: wave w, lane l: h = l&7, j-sub = l>>3; m extends j, n extends i ----
    const int w = t >> 6;
    const int l = t & 63;
    const int h = l & 7;

    float acc[4][4];
    #pragma unroll
    for (int m = 0; m < 4; ++m)
        #pragma unroll
        for (int n = 0; n < 4; ++n) acc[m][n] = 0.f;

    const h2 one2 = {(_Float16)1.f, (_Float16)1.f};

    const _Float16* qrow = qs + (size_t)l * PAD;
    const _Float16* krow = ks + (size_t)(8 * w + h) * PAD;

    #pragma unroll
    for (int w8 = 0; w8 < 8; ++w8) {
        u4 qd[4], kd[4];
        #pragma unroll
        for (int m = 0; m < 4; ++m)     // q row = l + 64m  (64 distinct, bank-tiled, 8cyc)
            qd[m] = *(const u4*)(qrow + (size_t)(64 * m) * PAD + 8 * w8);
        #pragma unroll
        for (int n = 0; n < 4; ++n)     // k row = 8w + 64n + h (8 distinct, broadcast)
            kd[n] = *(const u4*)(krow + (size_t)(64 * n) * PAD + 8 * w8);
        #pragma unroll
        for (int m = 0; m < 4; ++m)
            #pragma unroll
            for (int n = 0; n < 4; ++n)
                #pragma unroll
                for (int p = 0; p < 4; ++p) {
                    h2 a = __builtin_bit_cast(h2, (unsigned)qd[m][p]);
                    h2 c = __builtin_bit_cast(h2, (unsigned)kd[n][p]);
                    h2 d = a - c;                                   // v_pk_add_f16 (neg)
                    d = __builtin_bit_cast(h2,
                            __builtin_bit_cast(unsigned, d) & 0x7fff7fffu);  // packed |.|
                    acc[m][n] = __builtin_amdgcn_fdot2(d, one2, acc[m][n], false);
                }
    }

    // ---- stores: two halves so the first half's drain overlaps nothing worse;
    //      each store = 64 lanes x consecutive dwords (256 B) ----
    const float s = -0.125f;
    #pragma unroll
    for (int m = 0; m < 4; ++m) {
        #pragma unroll
        for (int n = 0; n < 4; ++n) {
            size_t base = (((size_t)b * NCTX + (i0 + w + 8 * n)) * NCTX + j0 + 8 * m) * NHEADS;
            out[base + l] = acc[m][n] * s;
        }
    }
}

extern "C" void kernel_launch(void* const* d_in, const int* in_sizes, int n_in,
                              void* d_out, int out_size, void* d_ws, size_t ws_size,
                              hipStream_t stream) {
    const float* q = (const float*)d_in[0];
    const float* k = (const float*)d_in[1];
    float* out = (float*)d_out;

    (void)hipFuncSetAttribute(reinterpret_cast<const void*>(l1attn_kernel),
                              hipFuncAttributeMaxDynamicSharedMemorySize, LDS_BYTES);

    l1attn_kernel<<<dim3(512), dim3(512), LDS_BYTES, stream>>>(q, k, out);
}